// Round 2
// baseline (733.246 us; speedup 1.0000x reference)
//
#include <hip/hip_runtime.h>
#include <hip/hip_bf16.h>

// SSA attention, B=1 S=4096 HID=4096 H=32 KV=8 D=128, fp32 in (detected),
// fp32 out. R6: 256x256x64 GEMM, m201-style phase rhythm (double barrier +
// lgkmcnt(0) before MFMA cluster), counted vmcnt, K-half granules, setprio.

typedef short bf16x8 __attribute__((ext_vector_type(8)));
typedef float f32x4 __attribute__((ext_vector_type(4)));
using bf16 = __hip_bfloat16;

#define S_LEN 4096
#define HIDN  4096
#define NH    32
#define NKV   8
#define DH    128
#define NBLK  64
#define SCALE 0.08838834764831845f

__device__ __forceinline__ void gload16(const bf16* g, bf16* l) {
  __builtin_amdgcn_global_load_lds(
      (const __attribute__((address_space(1))) unsigned int*)g,
      (__attribute__((address_space(3))) unsigned int*)l, 16, 0, 0);
}

// ---------------- dtype detector (fp32 vs bf16 inputs) ----------------
__global__ void k_detect(const unsigned short* __restrict__ w,
                         int* __restrict__ flag) {
  int t = threadIdx.x;
  unsigned short u = w[t];
  int e = (u >> 7) & 0xFF;
  int bad = (e >= 134) ? 1 : 0;
  __shared__ int cnt;
  if (t == 0) cnt = 0;
  __syncthreads();
  atomicAdd(&cnt, bad);
  __syncthreads();
  if (t == 0) flag[0] = (cnt > 32) ? 1 : 0;
}

// ---------------- convert (no transpose): in -> bf16 out ----------------
__global__ void k_cvt(const void* __restrict__ in, bf16* __restrict__ out,
                      const int* __restrict__ flagp, int n8) {
  int i = blockIdx.x * blockDim.x + threadIdx.x;
  if (i >= n8) return;
  if (*flagp) {
    const float4* p = (const float4*)in + (size_t)i * 2;
    float4 a = p[0], b = p[1];
    alignas(16) bf16 v[8] = {__float2bfloat16(a.x), __float2bfloat16(a.y),
                             __float2bfloat16(a.z), __float2bfloat16(a.w),
                             __float2bfloat16(b.x), __float2bfloat16(b.y),
                             __float2bfloat16(b.z), __float2bfloat16(b.w)};
    *(uint4*)(out + (size_t)i * 8) = *(const uint4*)v;
  } else {
    ((uint4*)out)[i] = ((const uint4*)in)[i];
  }
}

// ------ transpose+convert: w [K][N] -> wt bf16 [N][K], 64x64 tiles ------
__global__ __launch_bounds__(256) void k_tcvt(const void* __restrict__ w_,
                                              bf16* __restrict__ wt,
                                              const int* __restrict__ flagp,
                                              int K, int N) {
  __shared__ bf16 tile[64][66];  // [k][n], odd word-stride (33)
  const bool f32 = *flagp != 0;
  const int k0 = blockIdx.x * 64, n0 = blockIdx.y * 64;
  const int t = threadIdx.x;
  const int r = t >> 2, c16 = (t & 3) * 16;
  if (f32) {
    const float* src = (const float*)w_ + (size_t)(k0 + r) * N + n0 + c16;
    float4 a = ((const float4*)src)[0], b = ((const float4*)src)[1];
    float4 c = ((const float4*)src)[2], d = ((const float4*)src)[3];
    bf16* dst = &tile[r][c16];
    dst[0] = __float2bfloat16(a.x);  dst[1] = __float2bfloat16(a.y);
    dst[2] = __float2bfloat16(a.z);  dst[3] = __float2bfloat16(a.w);
    dst[4] = __float2bfloat16(b.x);  dst[5] = __float2bfloat16(b.y);
    dst[6] = __float2bfloat16(b.z);  dst[7] = __float2bfloat16(b.w);
    dst[8] = __float2bfloat16(c.x);  dst[9] = __float2bfloat16(c.y);
    dst[10] = __float2bfloat16(c.z); dst[11] = __float2bfloat16(c.w);
    dst[12] = __float2bfloat16(d.x); dst[13] = __float2bfloat16(d.y);
    dst[14] = __float2bfloat16(d.z); dst[15] = __float2bfloat16(d.w);
  } else {
    const bf16* src = (const bf16*)w_ + (size_t)(k0 + r) * N + n0 + c16;
    uint4 a = ((const uint4*)src)[0], b = ((const uint4*)src)[1];
    *(uint4*)(&tile[r][c16]) = a;
    *(uint4*)(&tile[r][c16 + 8]) = b;
  }
  __syncthreads();
  alignas(16) bf16 v[16];
#pragma unroll
  for (int j = 0; j < 16; j++) v[j] = tile[c16 + j][r];
  bf16* dst = wt + (size_t)(n0 + r) * K + k0 + c16;
  ((uint4*)dst)[0] = ((const uint4*)v)[0];
  ((uint4*)dst)[1] = ((const uint4*)v)[1];
}

// ---- GEMM: C[M][N] = A[M][K] * BT[N][K]^T, bf16, 256x256 tile, BK=64 ----
// 8 waves (2Mx4N), 128x64 per wave. LDS 128 KiB:
//   A[2 buf][2 khalf][256 rows][32 cols] | B same at elem offset 32768.
// Stage granule = one K-half of A or B (16 KB, 2 gload16/thread), linear
// LDS dest (global_load_lds requirement); the 16B-block permutation
// blk ^= (row>>1)&3 is applied on the GLOBAL source so ds_read_b128 frag
// reads are bank-conflict-free (measured 0).
// Phase rhythm (m201 template): {ds_read issue; stage issue; barrier;
// lgkmcnt(0); setprio(1); 16 MFMA; setprio(0); [vmcnt]; barrier}.
// Granule g=4kt+j issued at phase g-6 (after its region's last reader's
// drain barrier); vmcnt(8) at ends of phases 1 and 3 only (4 granules in
// flight), drained 8->4->0 in the last two K-tiles.
// kind 0: QKV routing (bf16; n<4096 -> outQ w4096, <5120 -> outK w1024,
//         else outV w1024).  kind 1: single output, fp32 if *flagp.
#define WAITV(N) asm volatile("s_waitcnt vmcnt(" #N ")" ::: "memory")
#define WAITL0() asm volatile("s_waitcnt lgkmcnt(0)" ::: "memory")
#define BARRIER()                                \
  do {                                           \
    asm volatile("" ::: "memory");               \
    __builtin_amdgcn_s_barrier();                \
    asm volatile("" ::: "memory");               \
  } while (0)

__global__ __launch_bounds__(512, 2) void k_gemm(
    const bf16* __restrict__ A, const bf16* __restrict__ BT,
    void* __restrict__ outQ, void* __restrict__ outK, void* __restrict__ outV,
    const int* __restrict__ flagp, int M, int N, int K, int kind) {
  __shared__ __align__(16) bf16 lds[65536];  // 128 KiB
  const int NT = K >> 6;
  const int mb = M >> 8;
  const int nwg = mb * (N >> 8);
  const int bid = blockIdx.y * gridDim.x + blockIdx.x;
  const int lin = (bid & 7) * (nwg >> 3) + (bid >> 3);  // XCD swizzle (nwg%8==0)
  const int m0 = (lin % mb) << 8;
  const int n0 = (lin / mb) << 8;
  const int t = threadIdx.x;
  const int wid = t >> 6, lane = t & 63, quad = lane >> 4, l16 = lane & 15;
  const int wr = wid >> 2, wc = wid & 3;
  const int sw = (quad ^ ((l16 >> 1) & 3)) * 8;  // swizzled 16B-block (elems)

  f32x4 acc[8][4] = {};
  bf16x8 a[4], bfr[4];

  auto stageHalf = [&](int g) {
    const int kt = g >> 2, j = g & 3;          // j: 0=A-k0 1=B-k0 2=A-k1 3=B-k1
    const int buf = kt & 1, isB = j & 1, kh = j >> 1;
    const bf16* src = isB ? BT : A;
    const int r0 = isB ? n0 : m0;
    const int base = (isB ? 32768 : 0) + buf * 16384 + kh * 8192;
    const int kcol = kt * 64 + kh * 32;
#pragma unroll
    for (int p = 0; p < 2; p++) {
      int u = p * 512 + t;                     // 16B unit within granule
      int r = u >> 2;                          // row 0..255
      int gb = (u & 3) ^ ((r >> 1) & 3);       // pre-swizzled global block
      gload16(src + (size_t)(r0 + r) * K + kcol + gb * 8, &lds[base + u * 8]);
    }
  };

#define READS(kt, KH, MH)                                                     \
  {                                                                           \
    const int abase = ((kt) & 1) * 16384 + (KH) * 8192;                       \
    _Pragma("unroll") for (int i = 0; i < 4; i++) a[i] =                      \
        *(const bf16x8*)&lds[abase +                                          \
                             (wr * 128 + ((MH) * 4 + i) * 16 + l16) * 32 +    \
                             sw];                                             \
    if ((MH) == 0) {                                                          \
      const int bbase = 32768 + ((kt) & 1) * 16384 + (KH) * 8192;             \
      _Pragma("unroll") for (int j = 0; j < 4; j++) bfr[j] =                  \
          *(const bf16x8*)&lds[bbase + (wc * 64 + j * 16 + l16) * 32 + sw];   \
    }                                                                         \
  }

#define MFMAS(MH)                                                             \
  {                                                                           \
    __builtin_amdgcn_s_setprio(1);                                            \
    _Pragma("unroll") for (int i = 0; i < 4; i++)                             \
        _Pragma("unroll") for (int j = 0; j < 4; j++) acc[(MH) * 4 + i][j] =  \
            __builtin_amdgcn_mfma_f32_16x16x32_bf16(                          \
                a[i], bfr[j], acc[(MH) * 4 + i][j], 0, 0, 0);                 \
    __builtin_amdgcn_s_setprio(0);                                            \
  }

  // prologue: granules g=0..5 (tile0 fully + tile1 k0 halves)
  stageHalf(0); stageHalf(1); stageHalf(2); stageHalf(3);
  stageHalf(4); stageHalf(5);
  WAITV(8);  // g0,g1 (tile0 k0 halves) landed; 4 granules in flight
  BARRIER();

  const int G = 4 * NT;
  for (int kt = 0; kt < NT; ++kt) {
    const int g = 4 * kt + 6;
    // phase 0: (k0, m-lo)
    READS(kt, 0, 0);
    if (g < G) stageHalf(g);          // A-k1(kt+1), region dead since kt-1
    BARRIER();
    WAITL0();
    MFMAS(0);
    BARRIER();
    // phase 1: (k0, m-hi)
    READS(kt, 0, 1);
    if (g + 1 < G) stageHalf(g + 1);  // B-k1(kt+1)
    BARRIER();
    WAITL0();
    MFMAS(1);
    if (kt < NT - 1) { WAITV(8); } else { WAITV(0); }  // k1(kt) landed
    BARRIER();
    // phase 2: (k1, m-lo)
    READS(kt, 1, 0);
    if (g + 2 < G) stageHalf(g + 2);  // A-k0(kt+2), k0(kt) retired at ph1
    BARRIER();
    WAITL0();
    MFMAS(0);
    BARRIER();
    // phase 3: (k1, m-hi)
    READS(kt, 1, 1);
    if (g + 3 < G) stageHalf(g + 3);  // B-k0(kt+2)
    BARRIER();
    WAITL0();
    MFMAS(1);
    if (kt < NT - 2) { WAITV(8); } else if (kt == NT - 2) { WAITV(4); }
    BARRIER();
  }

  const bool storeF32 = (kind == 1) && (*flagp != 0);
#pragma unroll
  for (int i = 0; i < 8; i++)
#pragma unroll
    for (int j = 0; j < 4; j++)
#pragma unroll
      for (int r = 0; r < 4; r++) {
        int m = m0 + wr * 128 + i * 16 + quad * 4 + r;
        int n = n0 + wc * 64 + j * 16 + l16;
        float v = acc[i][j][r];
        if (kind == 1) {
          if (storeF32)
            ((float*)outQ)[(size_t)m * N + n] = v;
          else
            ((bf16*)outQ)[(size_t)m * N + n] = __float2bfloat16(v);
        } else {
          bf16* Co;
          if (n < 4096)
            Co = (bf16*)outQ + (size_t)m * 4096 + n;
          else if (n < 5120)
            Co = (bf16*)outK + (size_t)m * 1024 + (n - 4096);
          else
            Co = (bf16*)outV + (size_t)m * 1024 + (n - 5120);
          *Co = __float2bfloat16(v);
        }
      }
}

// -------- RoPE in place, fused Q+K: x[s][nheads][128], pairs (j, j+64) ---
__global__ void k_rope(bf16* __restrict__ Q, bf16* __restrict__ Kb,
                       int totalQ, int total) {
  int idx = blockIdx.x * blockDim.x + threadIdx.x;
  if (idx >= total) return;
  bf16* x;
  int nheads, li;
  if (idx < totalQ) { x = Q; nheads = NH; li = idx; }
  else { x = Kb; nheads = NKV; li = idx - totalQ; }
  int j = li & 63;   // freq index
  int sh = li >> 6;  // s*nheads + head
  int s = sh / nheads;
  float invf = (float)exp(-(double)j * (9.210340371976184 / 64.0));
  float ang = (float)s * invf;
  float sn, cs;
  sincosf(ang, &sn, &cs);
  bf16* p = x + (size_t)sh * DH;
  float x1 = __bfloat162float(p[j]);
  float x2 = __bfloat162float(p[j + 64]);
  p[j]      = __float2bfloat16(x1 * cs - x2 * sn);
  p[j + 64] = __float2bfloat16(x2 * cs + x1 * sn);
}

// ---------------- attention: one block per (query-block nb, head h) ------
// local: causal window [q-64, q] (block-0 zero-pad keys included, score 0)
// landmark: landmarks 0..nb (positions 64*l), separate softmax, 0.7/0.3 mix
__global__ __launch_bounds__(256) void k_attn(const bf16* __restrict__ Q,
                                              const bf16* __restrict__ Kk,
                                              const bf16* __restrict__ V,
                                              bf16* __restrict__ O) {
  const int nb = blockIdx.x;
  const int h = blockIdx.y;
  const int kvh = h >> 2;
  const int t = threadIdx.x;
  const int wid = t >> 6, lane = t & 63, quad = lane >> 4, l16 = lane & 15;

  __shared__ bf16 Qs[64 * 136];   // Q tile; reused as P (exp weights)
  __shared__ bf16 kvb[128 * 136]; // K chunks [64][136] / Vt,LVt [128][72]
  __shared__ bf16 PLs[64 * 72];   // landmark exp weights

  const int srow16 = t >> 4, soff = (t & 15) * 8;

#pragma unroll
  for (int p = 0; p < 4; p++) {
    int row = p * 16 + srow16;
    *(uint4*)(&Qs[row * 136 + soff]) =
        *(const uint4*)(Q + ((size_t)(nb * 64 + row) * NH + h) * DH + soff);
  }

  auto stageK = [&](int basePos, int posStride) {
#pragma unroll
    for (int p = 0; p < 4; p++) {
      int row = p * 16 + srow16;
      int pos = basePos + row * posStride;
      uint4 val = make_uint4(0u, 0u, 0u, 0u);
      if (pos >= 0)
        val = *(const uint4*)(Kk + ((size_t)pos * NKV + kvh) * DH + soff);
      *(uint4*)(&kvb[row * 136 + soff]) = val;
    }
  };

  auto stageVt = [&](int basePos, int posStride) {
#pragma unroll
    for (int p = 0; p < 4; p++) {
      int key = p * 16 + srow16;
      int pos = basePos + key * posStride;
      uint4 tv = make_uint4(0u, 0u, 0u, 0u);
      if (pos >= 0)
        tv = *(const uint4*)(V + ((size_t)pos * NKV + kvh) * DH + soff);
      const bf16* tmp = (const bf16*)&tv;
#pragma unroll
      for (int jj = 0; jj < 8; jj++)
        kvb[(soff + jj) * 72 + key] = tmp[jj];
    }
  };

  f32x4 sc[8] = {};
  f32x4 slm[4] = {};

  auto scoreStep = [&](f32x4* dst) {
#pragma unroll
    for (int kk = 0; kk < 128; kk += 32) {
      bf16x8 a = *(const bf16x8*)(&Qs[(wid * 16 + l16) * 136 + kk + quad * 8]);
#pragma unroll
      for (int nt = 0; nt < 4; nt++) {
        bf16x8 b =
            *(const bf16x8*)(&kvb[(nt * 16 + l16) * 136 + kk + quad * 8]);
        dst[nt] = __builtin_amdgcn_mfma_f32_16x16x32_bf16(a, b, dst[nt], 0, 0, 0);
      }
    }
  };

  stageK(nb * 64 - 64, 1);
  __syncthreads();
  scoreStep(&sc[0]);
  __syncthreads();
  stageK(nb * 64, 1);
  __syncthreads();
  scoreStep(&sc[4]);
  __syncthreads();
  stageK(0, 64);
  __syncthreads();
  scoreStep(&slm[0]);
  __syncthreads();

  float invL[4], invG[4];
#pragma unroll
  for (int r = 0; r < 4; r++) {
    const int i = wid * 16 + quad * 4 + r;
    float mx = -1e30f;
#pragma unroll
    for (int nt = 0; nt < 8; nt++) {
      int j = nt * 16 + l16;
      float s = sc[nt][r] * SCALE;
      if (j < i || j > i + 64) s = -1e30f;
      sc[nt][r] = s;
      mx = fmaxf(mx, s);
    }
#pragma unroll
    for (int m = 1; m <= 8; m <<= 1) mx = fmaxf(mx, __shfl_xor(mx, m, 64));
    float sum = 0.f;
#pragma unroll
    for (int nt = 0; nt < 8; nt++) {
      float e = __expf(sc[nt][r] - mx);
      sc[nt][r] = e;
      sum += e;
    }
#pragma unroll
    for (int m = 1; m <= 8; m <<= 1) sum += __shfl_xor(sum, m, 64);
    invL[r] = 0.7f / sum;

    float mg = -1e30f;
#pragma unroll
    for (int nt = 0; nt < 4; nt++) {
      int l = nt * 16 + l16;
      float s = slm[nt][r] * SCALE;
      if (l > nb) s = -1e30f;
      slm[nt][r] = s;
      mg = fmaxf(mg, s);
    }
#pragma unroll
    for (int m = 1; m <= 8; m <<= 1) mg = fmaxf(mg, __shfl_xor(mg, m, 64));
    float sg = 0.f;
#pragma unroll
    for (int nt = 0; nt < 4; nt++) {
      float e = __expf(slm[nt][r] - mg);
      slm[nt][r] = e;
      sg += e;
    }
#pragma unroll
    for (int m = 1; m <= 8; m <<= 1) sg += __shfl_xor(sg, m, 64);
    invG[r] = 0.3f / sg;
  }

#pragma unroll
  for (int nt = 0; nt < 8; nt++)
#pragma unroll
    for (int r = 0; r < 4; r++)
      Qs[(wid * 16 + quad * 4 + r) * 136 + nt * 16 + l16] =
          __float2bfloat16(sc[nt][r]);
#pragma unroll
  for (int nt = 0; nt < 4; nt++)
#pragma unroll
    for (int r = 0; r < 4; r++)
      PLs[(wid * 16 + quad * 4 + r) * 72 + nt * 16 + l16] =
          __float2bfloat16(slm[nt][r]);
  stageVt(nb * 64 - 64, 1);
  __syncthreads();

  f32x4 accO[8] = {};
  f32x4 accG[8] = {};
  auto pvStep = [&](f32x4* dst, const bf16* Pbase, int pstride, int colbase) {
#pragma unroll
    for (int kk = 0; kk < 64; kk += 32) {
      bf16x8 a = *(const bf16x8*)(&Pbase[(wid * 16 + l16) * pstride + colbase +
                                         kk + quad * 8]);
#pragma unroll
      for (int nt = 0; nt < 8; nt++) {
        bf16x8 b = *(const bf16x8*)(&kvb[(nt * 16 + l16) * 72 + kk + quad * 8]);
        dst[nt] = __builtin_amdgcn_mfma_f32_16x16x32_bf16(a, b, dst[nt], 0, 0, 0);
      }
    }
  };
  pvStep(accO, Qs, 136, 0);
  __syncthreads();
  stageVt(nb * 64, 1);
  __syncthreads();
  pvStep(accO, Qs, 136, 64);
  __syncthreads();
  stageVt(0, 64);
  __syncthreads();
  pvStep(accG, PLs, 72, 0);

#pragma unroll
  for (int nt = 0; nt < 8; nt++)
#pragma unroll
    for (int r = 0; r < 4; r++) {
      int q = nb * 64 + wid * 16 + quad * 4 + r;
      int d = nt * 16 + l16;
      float v = accO[nt][r] * invL[r] + accG[nt][r] * invG[r];
      O[((size_t)q * NH + h) * DH + d] = __float2bfloat16(v);
    }
}

// ---------------- launch ----------------
extern "C" void kernel_launch(void* const* d_in, const int* in_sizes, int n_in,
                              void* d_out, int out_size, void* d_ws,
                              size_t ws_size, hipStream_t stream) {
  const void* X  = d_in[0];
  const void* wq = d_in[1];
  const void* wk = d_in[2];
  const void* wv = d_in[3];
  const void* wo = d_in[4];

  char* ws = (char*)d_ws;
  int* flag = (int*)ws;
  bf16* Xb   = (bf16*)(ws + 256);               // 32 MB ; aliased as At
  bf16* Wcat = Xb + (size_t)S_LEN * HIDN;       // 48 MB [6144][4096]
  bf16* Qb   = Wcat + (size_t)6144 * HIDN;      // 32 MB
  bf16* Kb   = Qb + (size_t)S_LEN * HIDN;       // 8 MB
  bf16* Vb   = Kb + (size_t)S_LEN * 1024;       // 8 MB
  bf16* At   = Xb;                              // alias (X dead after QKV)
  bf16* WoT  = Wcat;                            // alias (Wcat dead after QKV)

  k_detect<<<1, 256, 0, stream>>>((const unsigned short*)wq, flag);

  k_cvt<<<(S_LEN * HIDN / 8 + 255) / 256, 256, 0, stream>>>(
      X, Xb, flag, S_LEN * HIDN / 8);
  k_tcvt<<<dim3(HIDN / 64, HIDN / 64), 256, 0, stream>>>(
      wq, Wcat, flag, HIDN, HIDN);
  k_tcvt<<<dim3(HIDN / 64, 1024 / 64), 256, 0, stream>>>(
      wk, Wcat + (size_t)4096 * HIDN, flag, HIDN, 1024);
  k_tcvt<<<dim3(HIDN / 64, 1024 / 64), 256, 0, stream>>>(
      wv, Wcat + (size_t)5120 * HIDN, flag, HIDN, 1024);

  // fused QKV GEMM: [4096][4096] x [6144][4096]^T -> Qb|Kb|Vb
  k_gemm<<<dim3(S_LEN / 256, 6144 / 256), 512, 0, stream>>>(
      Xb, Wcat, Qb, Kb, Vb, flag, S_LEN, 6144, HIDN, 0);

  int totalQ = S_LEN * NH * 64, total = totalQ + S_LEN * NKV * 64;
  k_rope<<<(total + 255) / 256, 256, 0, stream>>>(Qb, Kb, totalQ, total);

  k_attn<<<dim3(NBLK, NH), 256, 0, stream>>>(Qb, Kb, Vb, At);

  k_tcvt<<<dim3(HIDN / 64, HIDN / 64), 256, 0, stream>>>(
      wo, WoT, flag, HIDN, HIDN);

  k_gemm<<<dim3(S_LEN / 256, HIDN / 256), 512, 0, stream>>>(
      At, WoT, d_out, nullptr, nullptr, flag, S_LEN, HIDN, HIDN, 1);
}

// Round 3
// 721.338 us; speedup vs baseline: 1.0165x; 1.0165x over previous
//
#include <hip/hip_runtime.h>
#include <hip/hip_bf16.h>

// SSA attention, B=1 S=4096 HID=4096 H=32 KV=8 D=128, fp32 in (detected),
// fp32 out. R7: 256x256x64 GEMM; register-double-buffered fragments with
// ds_reads issued ONE PHASE AHEAD (kills the WAR serialization that idled
// the matrix pipe in R5/R6), single barrier per phase, counted vmcnt(6).

typedef short bf16x8 __attribute__((ext_vector_type(8)));
typedef float f32x4 __attribute__((ext_vector_type(4)));
using bf16 = __hip_bfloat16;

#define S_LEN 4096
#define HIDN  4096
#define NH    32
#define NKV   8
#define DH    128
#define NBLK  64
#define SCALE 0.08838834764831845f

__device__ __forceinline__ void gload16(const bf16* g, bf16* l) {
  __builtin_amdgcn_global_load_lds(
      (const __attribute__((address_space(1))) unsigned int*)g,
      (__attribute__((address_space(3))) unsigned int*)l, 16, 0, 0);
}

// ---------------- dtype detector (fp32 vs bf16 inputs) ----------------
__global__ void k_detect(const unsigned short* __restrict__ w,
                         int* __restrict__ flag) {
  int t = threadIdx.x;
  unsigned short u = w[t];
  int e = (u >> 7) & 0xFF;
  int bad = (e >= 134) ? 1 : 0;
  __shared__ int cnt;
  if (t == 0) cnt = 0;
  __syncthreads();
  atomicAdd(&cnt, bad);
  __syncthreads();
  if (t == 0) flag[0] = (cnt > 32) ? 1 : 0;
}

// ---------------- convert (no transpose): in -> bf16 out ----------------
__global__ void k_cvt(const void* __restrict__ in, bf16* __restrict__ out,
                      const int* __restrict__ flagp, int n8) {
  int i = blockIdx.x * blockDim.x + threadIdx.x;
  if (i >= n8) return;
  if (*flagp) {
    const float4* p = (const float4*)in + (size_t)i * 2;
    float4 a = p[0], b = p[1];
    alignas(16) bf16 v[8] = {__float2bfloat16(a.x), __float2bfloat16(a.y),
                             __float2bfloat16(a.z), __float2bfloat16(a.w),
                             __float2bfloat16(b.x), __float2bfloat16(b.y),
                             __float2bfloat16(b.z), __float2bfloat16(b.w)};
    *(uint4*)(out + (size_t)i * 8) = *(const uint4*)v;
  } else {
    ((uint4*)out)[i] = ((const uint4*)in)[i];
  }
}

// ------ transpose+convert: w [K][N] -> wt bf16 [N][K], 64x64 tiles ------
__global__ __launch_bounds__(256) void k_tcvt(const void* __restrict__ w_,
                                              bf16* __restrict__ wt,
                                              const int* __restrict__ flagp,
                                              int K, int N) {
  __shared__ bf16 tile[64][66];  // [k][n], odd word-stride (33)
  const bool f32 = *flagp != 0;
  const int k0 = blockIdx.x * 64, n0 = blockIdx.y * 64;
  const int t = threadIdx.x;
  const int r = t >> 2, c16 = (t & 3) * 16;
  if (f32) {
    const float* src = (const float*)w_ + (size_t)(k0 + r) * N + n0 + c16;
    float4 a = ((const float4*)src)[0], b = ((const float4*)src)[1];
    float4 c = ((const float4*)src)[2], d = ((const float4*)src)[3];
    bf16* dst = &tile[r][c16];
    dst[0] = __float2bfloat16(a.x);  dst[1] = __float2bfloat16(a.y);
    dst[2] = __float2bfloat16(a.z);  dst[3] = __float2bfloat16(a.w);
    dst[4] = __float2bfloat16(b.x);  dst[5] = __float2bfloat16(b.y);
    dst[6] = __float2bfloat16(b.z);  dst[7] = __float2bfloat16(b.w);
    dst[8] = __float2bfloat16(c.x);  dst[9] = __float2bfloat16(c.y);
    dst[10] = __float2bfloat16(c.z); dst[11] = __float2bfloat16(c.w);
    dst[12] = __float2bfloat16(d.x); dst[13] = __float2bfloat16(d.y);
    dst[14] = __float2bfloat16(d.z); dst[15] = __float2bfloat16(d.w);
  } else {
    const bf16* src = (const bf16*)w_ + (size_t)(k0 + r) * N + n0 + c16;
    uint4 a = ((const uint4*)src)[0], b = ((const uint4*)src)[1];
    *(uint4*)(&tile[r][c16]) = a;
    *(uint4*)(&tile[r][c16 + 8]) = b;
  }
  __syncthreads();
  alignas(16) bf16 v[16];
#pragma unroll
  for (int j = 0; j < 16; j++) v[j] = tile[c16 + j][r];
  bf16* dst = wt + (size_t)(n0 + r) * K + k0 + c16;
  ((uint4*)dst)[0] = ((const uint4*)v)[0];
  ((uint4*)dst)[1] = ((const uint4*)v)[1];
}

// ---- GEMM: C[M][N] = A[M][K] * BT[N][K]^T, bf16, 256x256 tile, BK=64 ----
// 8 waves (2Mx4N), 128x64 per wave. LDS 128 KiB:
//   A[2 buf][2 khalf][256 rows][32 cols] | B same at elem offset 32768.
// Stage granule = one K-half of A or B (16 KB, 2 gload16/thread), linear
// LDS dest (global_load_lds requirement); 16B-block permutation
// blk ^= (row>>1)&3 applied on the GLOBAL source (bank-conflict-free reads,
// measured 0).
// Fragment registers are DOUBLE-BUFFERED (a0/a1 by phase parity, b0/b1 by
// k-half) and each phase issues the NEXT phase's ds_reads before its own
// MFMA cluster -> read issue+latency hides under the ~620cy MFMA window.
// Phase: {reads(P+1); stage(P+6); sched_barrier; MFMA(P); [vmcnt]; barrier}.
// vmcnt(6) at ends of ph0 (covers k1(kt) for ph1 reads) and ph2 (covers
// k0(kt+1) for ph3 reads); tail drains 6->4->0. Granule g staged at phase
// g-6, >=2 phases after its region's last read issue (race-verified).
// kind 0: QKV routing (bf16; n<4096 -> outQ w4096, <5120 -> outK w1024,
//         else outV w1024).  kind 1: single output, fp32 if *flagp.
#define WAITV(N) asm volatile("s_waitcnt vmcnt(" #N ")" ::: "memory")
#define SCHEDB() __builtin_amdgcn_sched_barrier(0)
#define BARRIER()                                \
  do {                                           \
    asm volatile("" ::: "memory");               \
    __builtin_amdgcn_s_barrier();                \
    asm volatile("" ::: "memory");               \
  } while (0)

__global__ __launch_bounds__(512, 2) void k_gemm(
    const bf16* __restrict__ A, const bf16* __restrict__ BT,
    void* __restrict__ outQ, void* __restrict__ outK, void* __restrict__ outV,
    const int* __restrict__ flagp, int M, int N, int K, int kind) {
  __shared__ __align__(16) bf16 lds[65536];  // 128 KiB
  const int NT = K >> 6;
  const int mb = M >> 8;
  const int nwg = mb * (N >> 8);
  const int bid = blockIdx.y * gridDim.x + blockIdx.x;
  const int lin = (bid & 7) * (nwg >> 3) + (bid >> 3);  // XCD swizzle (nwg%8==0)
  const int m0 = (lin % mb) << 8;
  const int n0 = (lin / mb) << 8;
  const int t = threadIdx.x;
  const int wid = t >> 6, lane = t & 63, quad = lane >> 4, l16 = lane & 15;
  const int wr = wid >> 2, wc = wid & 3;
  const int sw = (quad ^ ((l16 >> 1) & 3)) * 8;  // swizzled 16B-block (elems)

  f32x4 acc[8][4] = {};
  bf16x8 a0[4], a1[4], b0[4], b1[4];

  auto stageHalf = [&](int g) {
    const int kt = g >> 2, j = g & 3;          // j: 0=A-k0 1=B-k0 2=A-k1 3=B-k1
    const int buf = kt & 1, isB = j & 1, kh = j >> 1;
    const bf16* src = isB ? BT : A;
    const int r0 = isB ? n0 : m0;
    const int base = (isB ? 32768 : 0) + buf * 16384 + kh * 8192;
    const int kcol = kt * 64 + kh * 32;
#pragma unroll
    for (int p = 0; p < 2; p++) {
      int u = p * 512 + t;                     // 16B unit within granule
      int r = u >> 2;                          // row 0..255
      int gb = (u & 3) ^ ((r >> 1) & 3);       // pre-swizzled global block
      gload16(src + (size_t)(r0 + r) * K + kcol + gb * 8, &lds[base + u * 8]);
    }
  };

#define RDA(d, BUF, KH, MH)                                                   \
  {                                                                           \
    const int abase = (BUF) * 16384 + (KH) * 8192;                            \
    _Pragma("unroll") for (int i = 0; i < 4; i++) d[i] =                      \
        *(const bf16x8*)&lds[abase +                                          \
                             (wr * 128 + ((MH) * 4 + i) * 16 + l16) * 32 +    \
                             sw];                                             \
  }
#define RDB(d, BUF, KH)                                                       \
  {                                                                           \
    const int bbase = 32768 + (BUF) * 16384 + (KH) * 8192;                    \
    _Pragma("unroll") for (int j = 0; j < 4; j++) d[j] =                      \
        *(const bf16x8*)&lds[bbase + (wc * 64 + j * 16 + l16) * 32 + sw];     \
  }
#define MF(AS, BS, MH)                                                        \
  {                                                                           \
    __builtin_amdgcn_s_setprio(1);                                            \
    _Pragma("unroll") for (int i = 0; i < 4; i++)                             \
        _Pragma("unroll") for (int j = 0; j < 4; j++) acc[(MH) * 4 + i][j] =  \
            __builtin_amdgcn_mfma_f32_16x16x32_bf16(                          \
                AS[i], BS[j], acc[(MH) * 4 + i][j], 0, 0, 0);                 \
    __builtin_amdgcn_s_setprio(0);                                            \
  }

  // prologue: granules g=0..5 (tile0 fully + tile1 k0 halves)
  stageHalf(0); stageHalf(1); stageHalf(2); stageHalf(3);
  stageHalf(4); stageHalf(5);
  WAITV(8);  // granules 0,1 (k0 of tile0) landed; 4 granules in flight
  BARRIER();
  RDA(a0, 0, 0, 0);  // phase-0 fragments
  RDB(b0, 0, 0);

  const int G = 4 * NT;
  for (int kt = 0; kt < NT; ++kt) {
    const int buf = kt & 1, nbuf = buf ^ 1;
    const int g = 4 * kt + 6;
    // ph0: consume (k0, m-lo) = a0 x b0
    RDA(a1, buf, 0, 1);               // fragments for ph1
    if (g < G) stageHalf(g);          // A-k1(kt+1)
    SCHEDB();
    MF(a0, b0, 0);
    if (kt < NT - 1) { WAITV(6); } else { WAITV(0); }  // k1(kt) landed
    BARRIER();
    // ph1: (k0, m-hi) = a1 x b0
    RDA(a0, buf, 1, 0);               // fragments for ph2
    RDB(b1, buf, 1);
    if (g + 1 < G) stageHalf(g + 1);  // B-k1(kt+1)
    SCHEDB();
    MF(a1, b0, 1);
    BARRIER();
    // ph2: (k1, m-lo) = a0 x b1
    RDA(a1, buf, 1, 1);               // fragments for ph3
    if (g + 2 < G) stageHalf(g + 2);  // A-k0(kt+2)
    SCHEDB();
    MF(a0, b1, 0);
    if (kt < NT - 2) { WAITV(6); } else if (kt == NT - 2) { WAITV(4); }
    BARRIER();
    // ph3: (k1, m-hi) = a1 x b1
    if (kt < NT - 1) {                // fragments for next tile's ph0
      RDA(a0, nbuf, 0, 0);
      RDB(b0, nbuf, 0);
    }
    if (g + 3 < G) stageHalf(g + 3);  // B-k0(kt+2)
    SCHEDB();
    MF(a1, b1, 1);
    BARRIER();
  }

  const bool storeF32 = (kind == 1) && (*flagp != 0);
#pragma unroll
  for (int i = 0; i < 8; i++)
#pragma unroll
    for (int j = 0; j < 4; j++)
#pragma unroll
      for (int r = 0; r < 4; r++) {
        int m = m0 + wr * 128 + i * 16 + quad * 4 + r;
        int n = n0 + wc * 64 + j * 16 + l16;
        float v = acc[i][j][r];
        if (kind == 1) {
          if (storeF32)
            ((float*)outQ)[(size_t)m * N + n] = v;
          else
            ((bf16*)outQ)[(size_t)m * N + n] = __float2bfloat16(v);
        } else {
          bf16* Co;
          if (n < 4096)
            Co = (bf16*)outQ + (size_t)m * 4096 + n;
          else if (n < 5120)
            Co = (bf16*)outK + (size_t)m * 1024 + (n - 4096);
          else
            Co = (bf16*)outV + (size_t)m * 1024 + (n - 5120);
          *Co = __float2bfloat16(v);
        }
      }
}

// -------- RoPE in place, fused Q+K: x[s][nheads][128], pairs (j, j+64) ---
__global__ void k_rope(bf16* __restrict__ Q, bf16* __restrict__ Kb,
                       int totalQ, int total) {
  int idx = blockIdx.x * blockDim.x + threadIdx.x;
  if (idx >= total) return;
  bf16* x;
  int nheads, li;
  if (idx < totalQ) { x = Q; nheads = NH; li = idx; }
  else { x = Kb; nheads = NKV; li = idx - totalQ; }
  int j = li & 63;   // freq index
  int sh = li >> 6;  // s*nheads + head
  int s = sh / nheads;
  float invf = (float)exp(-(double)j * (9.210340371976184 / 64.0));
  float ang = (float)s * invf;
  float sn, cs;
  sincosf(ang, &sn, &cs);
  bf16* p = x + (size_t)sh * DH;
  float x1 = __bfloat162float(p[j]);
  float x2 = __bfloat162float(p[j + 64]);
  p[j]      = __float2bfloat16(x1 * cs - x2 * sn);
  p[j + 64] = __float2bfloat16(x2 * cs + x1 * sn);
}

// ---------------- attention: one block per (query-block nb, head h) ------
// local: causal window [q-64, q] (block-0 zero-pad keys included, score 0)
// landmark: landmarks 0..nb (positions 64*l), separate softmax, 0.7/0.3 mix
__global__ __launch_bounds__(256) void k_attn(const bf16* __restrict__ Q,
                                              const bf16* __restrict__ Kk,
                                              const bf16* __restrict__ V,
                                              bf16* __restrict__ O) {
  const int nb = blockIdx.x;
  const int h = blockIdx.y;
  const int kvh = h >> 2;
  const int t = threadIdx.x;
  const int wid = t >> 6, lane = t & 63, quad = lane >> 4, l16 = lane & 15;

  __shared__ bf16 Qs[64 * 136];   // Q tile; reused as P (exp weights)
  __shared__ bf16 kvb[128 * 136]; // K chunks [64][136] / Vt,LVt [128][72]
  __shared__ bf16 PLs[64 * 72];   // landmark exp weights

  const int srow16 = t >> 4, soff = (t & 15) * 8;

#pragma unroll
  for (int p = 0; p < 4; p++) {
    int row = p * 16 + srow16;
    *(uint4*)(&Qs[row * 136 + soff]) =
        *(const uint4*)(Q + ((size_t)(nb * 64 + row) * NH + h) * DH + soff);
  }

  auto stageK = [&](int basePos, int posStride) {
#pragma unroll
    for (int p = 0; p < 4; p++) {
      int row = p * 16 + srow16;
      int pos = basePos + row * posStride;
      uint4 val = make_uint4(0u, 0u, 0u, 0u);
      if (pos >= 0)
        val = *(const uint4*)(Kk + ((size_t)pos * NKV + kvh) * DH + soff);
      *(uint4*)(&kvb[row * 136 + soff]) = val;
    }
  };

  auto stageVt = [&](int basePos, int posStride) {
#pragma unroll
    for (int p = 0; p < 4; p++) {
      int key = p * 16 + srow16;
      int pos = basePos + key * posStride;
      uint4 tv = make_uint4(0u, 0u, 0u, 0u);
      if (pos >= 0)
        tv = *(const uint4*)(V + ((size_t)pos * NKV + kvh) * DH + soff);
      const bf16* tmp = (const bf16*)&tv;
#pragma unroll
      for (int jj = 0; jj < 8; jj++)
        kvb[(soff + jj) * 72 + key] = tmp[jj];
    }
  };

  f32x4 sc[8] = {};
  f32x4 slm[4] = {};

  auto scoreStep = [&](f32x4* dst) {
#pragma unroll
    for (int kk = 0; kk < 128; kk += 32) {
      bf16x8 a = *(const bf16x8*)(&Qs[(wid * 16 + l16) * 136 + kk + quad * 8]);
#pragma unroll
      for (int nt = 0; nt < 4; nt++) {
        bf16x8 b =
            *(const bf16x8*)(&kvb[(nt * 16 + l16) * 136 + kk + quad * 8]);
        dst[nt] = __builtin_amdgcn_mfma_f32_16x16x32_bf16(a, b, dst[nt], 0, 0, 0);
      }
    }
  };

  stageK(nb * 64 - 64, 1);
  __syncthreads();
  scoreStep(&sc[0]);
  __syncthreads();
  stageK(nb * 64, 1);
  __syncthreads();
  scoreStep(&sc[4]);
  __syncthreads();
  stageK(0, 64);
  __syncthreads();
  scoreStep(&slm[0]);
  __syncthreads();

  float invL[4], invG[4];
#pragma unroll
  for (int r = 0; r < 4; r++) {
    const int i = wid * 16 + quad * 4 + r;
    float mx = -1e30f;
#pragma unroll
    for (int nt = 0; nt < 8; nt++) {
      int j = nt * 16 + l16;
      float s = sc[nt][r] * SCALE;
      if (j < i || j > i + 64) s = -1e30f;
      sc[nt][r] = s;
      mx = fmaxf(mx, s);
    }
#pragma unroll
    for (int m = 1; m <= 8; m <<= 1) mx = fmaxf(mx, __shfl_xor(mx, m, 64));
    float sum = 0.f;
#pragma unroll
    for (int nt = 0; nt < 8; nt++) {
      float e = __expf(sc[nt][r] - mx);
      sc[nt][r] = e;
      sum += e;
    }
#pragma unroll
    for (int m = 1; m <= 8; m <<= 1) sum += __shfl_xor(sum, m, 64);
    invL[r] = 0.7f / sum;

    float mg = -1e30f;
#pragma unroll
    for (int nt = 0; nt < 4; nt++) {
      int l = nt * 16 + l16;
      float s = slm[nt][r] * SCALE;
      if (l > nb) s = -1e30f;
      slm[nt][r] = s;
      mg = fmaxf(mg, s);
    }
#pragma unroll
    for (int m = 1; m <= 8; m <<= 1) mg = fmaxf(mg, __shfl_xor(mg, m, 64));
    float sg = 0.f;
#pragma unroll
    for (int nt = 0; nt < 4; nt++) {
      float e = __expf(slm[nt][r] - mg);
      slm[nt][r] = e;
      sg += e;
    }
#pragma unroll
    for (int m = 1; m <= 8; m <<= 1) sg += __shfl_xor(sg, m, 64);
    invG[r] = 0.3f / sg;
  }

#pragma unroll
  for (int nt = 0; nt < 8; nt++)
#pragma unroll
    for (int r = 0; r < 4; r++)
      Qs[(wid * 16 + quad * 4 + r) * 136 + nt * 16 + l16] =
          __float2bfloat16(sc[nt][r]);
#pragma unroll
  for (int nt = 0; nt < 4; nt++)
#pragma unroll
    for (int r = 0; r < 4; r++)
      PLs[(wid * 16 + quad * 4 + r) * 72 + nt * 16 + l16] =
          __float2bfloat16(slm[nt][r]);
  stageVt(nb * 64 - 64, 1);
  __syncthreads();

  f32x4 accO[8] = {};
  f32x4 accG[8] = {};
  auto pvStep = [&](f32x4* dst, const bf16* Pbase, int pstride, int colbase) {
#pragma unroll
    for (int kk = 0; kk < 64; kk += 32) {
      bf16x8 a = *(const bf16x8*)(&Pbase[(wid * 16 + l16) * pstride + colbase +
                                         kk + quad * 8]);
#pragma unroll
      for (int nt = 0; nt < 8; nt++) {
        bf16x8 b = *(const bf16x8*)(&kvb[(nt * 16 + l16) * 72 + kk + quad * 8]);
        dst[nt] = __builtin_amdgcn_mfma_f32_16x16x32_bf16(a, b, dst[nt], 0, 0, 0);
      }
    }
  };
  pvStep(accO, Qs, 136, 0);
  __syncthreads();
  stageVt(nb * 64, 1);
  __syncthreads();
  pvStep(accO, Qs, 136, 64);
  __syncthreads();
  stageVt(0, 64);
  __syncthreads();
  pvStep(accG, PLs, 72, 0);

#pragma unroll
  for (int nt = 0; nt < 8; nt++)
#pragma unroll
    for (int r = 0; r < 4; r++) {
      int q = nb * 64 + wid * 16 + quad * 4 + r;
      int d = nt * 16 + l16;
      float v = accO[nt][r] * invL[r] + accG[nt][r] * invG[r];
      O[((size_t)q * NH + h) * DH + d] = __float2bfloat16(v);
    }
}

// ---------------- launch ----------------
extern "C" void kernel_launch(void* const* d_in, const int* in_sizes, int n_in,
                              void* d_out, int out_size, void* d_ws,
                              size_t ws_size, hipStream_t stream) {
  const void* X  = d_in[0];
  const void* wq = d_in[1];
  const void* wk = d_in[2];
  const void* wv = d_in[3];
  const void* wo = d_in[4];

  char* ws = (char*)d_ws;
  int* flag = (int*)ws;
  bf16* Xb   = (bf16*)(ws + 256);               // 32 MB ; aliased as At
  bf16* Wcat = Xb + (size_t)S_LEN * HIDN;       // 48 MB [6144][4096]
  bf16* Qb   = Wcat + (size_t)6144 * HIDN;      // 32 MB
  bf16* Kb   = Qb + (size_t)S_LEN * HIDN;       // 8 MB
  bf16* Vb   = Kb + (size_t)S_LEN * 1024;       // 8 MB
  bf16* At   = Xb;                              // alias (X dead after QKV)
  bf16* WoT  = Wcat;                            // alias (Wcat dead after QKV)

  k_detect<<<1, 256, 0, stream>>>((const unsigned short*)wq, flag);

  k_cvt<<<(S_LEN * HIDN / 8 + 255) / 256, 256, 0, stream>>>(
      X, Xb, flag, S_LEN * HIDN / 8);
  k_tcvt<<<dim3(HIDN / 64, HIDN / 64), 256, 0, stream>>>(
      wq, Wcat, flag, HIDN, HIDN);
  k_tcvt<<<dim3(HIDN / 64, 1024 / 64), 256, 0, stream>>>(
      wk, Wcat + (size_t)4096 * HIDN, flag, HIDN, 1024);
  k_tcvt<<<dim3(HIDN / 64, 1024 / 64), 256, 0, stream>>>(
      wv, Wcat + (size_t)5120 * HIDN, flag, HIDN, 1024);

  // fused QKV GEMM: [4096][4096] x [6144][4096]^T -> Qb|Kb|Vb
  k_gemm<<<dim3(S_LEN / 256, 6144 / 256), 512, 0, stream>>>(
      Xb, Wcat, Qb, Kb, Vb, flag, S_LEN, 6144, HIDN, 0);

  int totalQ = S_LEN * NH * 64, total = totalQ + S_LEN * NKV * 64;
  k_rope<<<(total + 255) / 256, 256, 0, stream>>>(Qb, Kb, totalQ, total);

  k_attn<<<dim3(NBLK, NH), 256, 0, stream>>>(Qb, Kb, Vb, At);

  k_tcvt<<<dim3(HIDN / 64, HIDN / 64), 256, 0, stream>>>(
      wo, WoT, flag, HIDN, HIDN);

  k_gemm<<<dim3(S_LEN / 256, HIDN / 256), 512, 0, stream>>>(
      At, WoT, d_out, nullptr, nullptr, flag, S_LEN, HIDN, HIDN, 1);
}

// Round 5
// 694.894 us; speedup vs baseline: 1.0552x; 1.0381x over previous
//
#include <hip/hip_runtime.h>
#include <hip/hip_bf16.h>

// SSA attention, B=1 S=4096 HID=4096 H=32 KV=8 D=128, fp32 in (detected),
// fp32 out. R8 (resubmit after infra failure): GEMM with 2 fat phases per
// K-tile (fewer barrier/drain events; R5's best-measured structure, merged)
// + grid balance via template<BN>: QKV 256x128 (768 blk = 3.0 rounds),
// WO 256x256 (256 = 1.0 rounds).

typedef short bf16x8 __attribute__((ext_vector_type(8)));
typedef float f32x4 __attribute__((ext_vector_type(4)));
using bf16 = __hip_bfloat16;

#define S_LEN 4096
#define HIDN  4096
#define NH    32
#define NKV   8
#define DH    128
#define NBLK  64
#define SCALE 0.08838834764831845f

__device__ __forceinline__ void gload16(const bf16* g, bf16* l) {
  __builtin_amdgcn_global_load_lds(
      (const __attribute__((address_space(1))) unsigned int*)g,
      (__attribute__((address_space(3))) unsigned int*)l, 16, 0, 0);
}

// ---------------- dtype detector (fp32 vs bf16 inputs) ----------------
__global__ void k_detect(const unsigned short* __restrict__ w,
                         int* __restrict__ flag) {
  int t = threadIdx.x;
  unsigned short u = w[t];
  int e = (u >> 7) & 0xFF;
  int bad = (e >= 134) ? 1 : 0;
  __shared__ int cnt;
  if (t == 0) cnt = 0;
  __syncthreads();
  atomicAdd(&cnt, bad);
  __syncthreads();
  if (t == 0) flag[0] = (cnt > 32) ? 1 : 0;
}

// ---------------- convert (no transpose): in -> bf16 out ----------------
__global__ void k_cvt(const void* __restrict__ in, bf16* __restrict__ out,
                      const int* __restrict__ flagp, int n8) {
  int i = blockIdx.x * blockDim.x + threadIdx.x;
  if (i >= n8) return;
  if (*flagp) {
    const float4* p = (const float4*)in + (size_t)i * 2;
    float4 a = p[0], b = p[1];
    alignas(16) bf16 v[8] = {__float2bfloat16(a.x), __float2bfloat16(a.y),
                             __float2bfloat16(a.z), __float2bfloat16(a.w),
                             __float2bfloat16(b.x), __float2bfloat16(b.y),
                             __float2bfloat16(b.z), __float2bfloat16(b.w)};
    *(uint4*)(out + (size_t)i * 8) = *(const uint4*)v;
  } else {
    ((uint4*)out)[i] = ((const uint4*)in)[i];
  }
}

// ------ transpose+convert: w [K][N] -> wt bf16 [N][K], 64x64 tiles ------
__global__ __launch_bounds__(256) void k_tcvt(const void* __restrict__ w_,
                                              bf16* __restrict__ wt,
                                              const int* __restrict__ flagp,
                                              int K, int N) {
  __shared__ bf16 tile[64][66];  // [k][n], odd word-stride (33)
  const bool f32 = *flagp != 0;
  const int k0 = blockIdx.x * 64, n0 = blockIdx.y * 64;
  const int t = threadIdx.x;
  const int r = t >> 2, c16 = (t & 3) * 16;
  if (f32) {
    const float* src = (const float*)w_ + (size_t)(k0 + r) * N + n0 + c16;
    float4 a = ((const float4*)src)[0], b = ((const float4*)src)[1];
    float4 c = ((const float4*)src)[2], d = ((const float4*)src)[3];
    bf16* dst = &tile[r][c16];
    dst[0] = __float2bfloat16(a.x);  dst[1] = __float2bfloat16(a.y);
    dst[2] = __float2bfloat16(a.z);  dst[3] = __float2bfloat16(a.w);
    dst[4] = __float2bfloat16(b.x);  dst[5] = __float2bfloat16(b.y);
    dst[6] = __float2bfloat16(b.z);  dst[7] = __float2bfloat16(b.w);
    dst[8] = __float2bfloat16(c.x);  dst[9] = __float2bfloat16(c.y);
    dst[10] = __float2bfloat16(c.z); dst[11] = __float2bfloat16(c.w);
    dst[12] = __float2bfloat16(d.x); dst[13] = __float2bfloat16(d.y);
    dst[14] = __float2bfloat16(d.z); dst[15] = __float2bfloat16(d.w);
  } else {
    const bf16* src = (const bf16*)w_ + (size_t)(k0 + r) * N + n0 + c16;
    uint4 a = ((const uint4*)src)[0], b = ((const uint4*)src)[1];
    *(uint4*)(&tile[r][c16]) = a;
    *(uint4*)(&tile[r][c16 + 8]) = b;
  }
  __syncthreads();
  alignas(16) bf16 v[16];
#pragma unroll
  for (int j = 0; j < 16; j++) v[j] = tile[c16 + j][r];
  bf16* dst = wt + (size_t)(n0 + r) * K + k0 + c16;
  ((uint4*)dst)[0] = ((const uint4*)v)[0];
  ((uint4*)dst)[1] = ((const uint4*)v)[1];
}

// ---- GEMM: C[M][N] = A[M][K] * BT[N][K]^T, bf16, 256xBN tile, BK=64 ----
// 8 waves; BN=256: 2Mx4N (per-wave 128x64, acc[8][4]); BN=128: 4Mx2N
// (per-wave 64x64, acc[4][4]). LDS: A 2buf x 2khalf x 256x32 (64KB), B at
// elem 32768: 2buf x 2khalf x BNx32.
// TWO fat phases per K-tile (one per K-half): {rdA+rdB (AF+4 ds_read_b128);
// stage next tile's same K-half (A:2 + B:2|1 gload16); setprio(1); all
// AFx4 MFMA; setprio(0); WAITV(L); barrier}.  L = 4 (BN=256) / 3 (BN=128).
// Invariant at each phase start: current K-half landed, next K-half in
// flight (L). Stage targets a region whose last readers completed >=1
// barrier earlier (ds_reads complete before the consuming MFMA issues).
// 16B-block permutation blk ^= (row>>1)&3 on the GLOBAL source keeps
// ds_read_b128 bank-conflict-free (measured 0).
// kind 0: QKV routing (bf16; n<4096 -> outQ w4096, <5120 -> outK w1024,
//         else outV w1024).  kind 1: single output, fp32 if *flagp.
#define WAITV(N) asm volatile("s_waitcnt vmcnt(" #N ")" ::: "memory")
#define BARRIER()                                \
  do {                                           \
    asm volatile("" ::: "memory");               \
    __builtin_amdgcn_s_barrier();                \
    asm volatile("" ::: "memory");               \
  } while (0)

template <int BN>
__global__ __launch_bounds__(512, 2) void k_gemm(
    const bf16* __restrict__ A, const bf16* __restrict__ BT,
    void* __restrict__ outQ, void* __restrict__ outK, void* __restrict__ outV,
    const int* __restrict__ flagp, int M, int N, int K, int kind) {
  constexpr int AF = (BN == 256) ? 8 : 4;   // A frags per wave
  constexpr int BL = (BN == 256) ? 2 : 1;   // B gload16 per thread per khalf
  constexpr int BKH = BN * 32;              // B khalf elems
  __shared__ __align__(16) bf16 lds[32768 + 4 * BKH];
  const int NT = K >> 6;
  const int mb = M >> 8;
  const int nwg = mb * (N / BN);
  const int bid = blockIdx.y * gridDim.x + blockIdx.x;
  const int lin = (bid & 7) * (nwg >> 3) + (bid >> 3);  // XCD swizzle (nwg%8==0)
  const int m0 = (lin % mb) << 8;
  const int n0 = (lin / mb) * BN;
  const int t = threadIdx.x;
  const int wid = t >> 6, lane = t & 63, quad = lane >> 4, l16 = lane & 15;
  const int wr = (BN == 256) ? (wid >> 2) : (wid >> 1);
  const int wc = (BN == 256) ? (wid & 3) : (wid & 1);
  const int sw = (quad ^ ((l16 >> 1) & 3)) * 8;  // swizzled 16B-block (elems)

  f32x4 acc[AF][4] = {};
  bf16x8 a[AF], b[4];

  auto stageA = [&](int kt, int kh) {
    const int base = (kt & 1) * 16384 + kh * 8192;
    const int kcol = kt * 64 + kh * 32;
#pragma unroll
    for (int p = 0; p < 2; p++) {
      int u = p * 512 + t;                 // 16B unit; 1024 units = 256 rows
      int r = u >> 2;
      int gb = (u & 3) ^ ((r >> 1) & 3);   // pre-swizzled global block
      gload16(A + (size_t)(m0 + r) * K + kcol + gb * 8, &lds[base + u * 8]);
    }
  };
  auto stageB = [&](int kt, int kh) {
    const int base = 32768 + (kt & 1) * (2 * BKH) + kh * BKH;
    const int kcol = kt * 64 + kh * 32;
#pragma unroll
    for (int p = 0; p < BL; p++) {
      int u = p * 512 + t;                 // BL*512 units = BN rows
      int r = u >> 2;
      int gb = (u & 3) ^ ((r >> 1) & 3);
      gload16(BT + (size_t)(n0 + r) * K + kcol + gb * 8, &lds[base + u * 8]);
    }
  };
  auto rdAB = [&](int buf, int kh) {
    const int abase = buf * 16384 + kh * 8192;
#pragma unroll
    for (int i = 0; i < AF; i++)
      a[i] = *(const bf16x8*)&lds[abase + (wr * (AF * 16) + i * 16 + l16) * 32 + sw];
    const int bbase = 32768 + buf * (2 * BKH) + kh * BKH;
#pragma unroll
    for (int j = 0; j < 4; j++)
      b[j] = *(const bf16x8*)&lds[bbase + (wc * 64 + j * 16 + l16) * 32 + sw];
  };

#define MFMA_ALL()                                                            \
  {                                                                           \
    __builtin_amdgcn_s_setprio(1);                                            \
    _Pragma("unroll") for (int i = 0; i < AF; i++)                            \
        _Pragma("unroll") for (int j = 0; j < 4; j++) acc[i][j] =             \
            __builtin_amdgcn_mfma_f32_16x16x32_bf16(a[i], b[j], acc[i][j],    \
                                                    0, 0, 0);                 \
    __builtin_amdgcn_s_setprio(0);                                            \
  }

  // prologue: tile0 both K-halves; wait for k-half 0 (L loads of kh1 remain)
  stageA(0, 0); stageB(0, 0);
  stageA(0, 1); stageB(0, 1);
  if constexpr (BN == 256) { WAITV(4); } else { WAITV(3); }
  BARRIER();

  for (int kt = 0; kt < NT; ++kt) {
    const int buf = kt & 1;
    // phase 0: K-half 0
    rdAB(buf, 0);
    if (kt + 1 < NT) { stageA(kt + 1, 0); stageB(kt + 1, 0); }
    MFMA_ALL();
    if (kt + 1 < NT) {
      if constexpr (BN == 256) { WAITV(4); } else { WAITV(3); }
    } else {
      WAITV(0);
    }
    BARRIER();
    // phase 1: K-half 1
    rdAB(buf, 1);
    if (kt + 1 < NT) { stageA(kt + 1, 1); stageB(kt + 1, 1); }
    MFMA_ALL();
    if (kt + 1 < NT) {
      if constexpr (BN == 256) { WAITV(4); } else { WAITV(3); }
    }
    BARRIER();
  }

  const bool storeF32 = (kind == 1) && (*flagp != 0);
#pragma unroll
  for (int i = 0; i < AF; i++)
#pragma unroll
    for (int j = 0; j < 4; j++)
#pragma unroll
      for (int r = 0; r < 4; r++) {
        int m = m0 + wr * (AF * 16) + i * 16 + quad * 4 + r;
        int n = n0 + wc * 64 + j * 16 + l16;
        float v = acc[i][j][r];
        if (kind == 1) {
          if (storeF32)
            ((float*)outQ)[(size_t)m * N + n] = v;
          else
            ((bf16*)outQ)[(size_t)m * N + n] = __float2bfloat16(v);
        } else {
          bf16* Co;
          if (n < 4096)
            Co = (bf16*)outQ + (size_t)m * 4096 + n;
          else if (n < 5120)
            Co = (bf16*)outK + (size_t)m * 1024 + (n - 4096);
          else
            Co = (bf16*)outV + (size_t)m * 1024 + (n - 5120);
          *Co = __float2bfloat16(v);
        }
      }
}

// -------- RoPE in place, fused Q+K: x[s][nheads][128], pairs (j, j+64) ---
__global__ void k_rope(bf16* __restrict__ Q, bf16* __restrict__ Kb,
                       int totalQ, int total) {
  int idx = blockIdx.x * blockDim.x + threadIdx.x;
  if (idx >= total) return;
  bf16* x;
  int nheads, li;
  if (idx < totalQ) { x = Q; nheads = NH; li = idx; }
  else { x = Kb; nheads = NKV; li = idx - totalQ; }
  int j = li & 63;   // freq index
  int sh = li >> 6;  // s*nheads + head
  int s = sh / nheads;
  float invf = (float)exp(-(double)j * (9.210340371976184 / 64.0));
  float ang = (float)s * invf;
  float sn, cs;
  sincosf(ang, &sn, &cs);
  bf16* p = x + (size_t)sh * DH;
  float x1 = __bfloat162float(p[j]);
  float x2 = __bfloat162float(p[j + 64]);
  p[j]      = __float2bfloat16(x1 * cs - x2 * sn);
  p[j + 64] = __float2bfloat16(x2 * cs + x1 * sn);
}

// ---------------- attention: one block per (query-block nb, head h) ------
// local: causal window [q-64, q] (block-0 zero-pad keys included, score 0)
// landmark: landmarks 0..nb (positions 64*l), separate softmax, 0.7/0.3 mix
__global__ __launch_bounds__(256) void k_attn(const bf16* __restrict__ Q,
                                              const bf16* __restrict__ Kk,
                                              const bf16* __restrict__ V,
                                              bf16* __restrict__ O) {
  const int nb = blockIdx.x;
  const int h = blockIdx.y;
  const int kvh = h >> 2;
  const int t = threadIdx.x;
  const int wid = t >> 6, lane = t & 63, quad = lane >> 4, l16 = lane & 15;

  __shared__ bf16 Qs[64 * 136];   // Q tile; reused as P (exp weights)
  __shared__ bf16 kvb[128 * 136]; // K chunks [64][136] / Vt,LVt [128][72]
  __shared__ bf16 PLs[64 * 72];   // landmark exp weights

  const int srow16 = t >> 4, soff = (t & 15) * 8;

#pragma unroll
  for (int p = 0; p < 4; p++) {
    int row = p * 16 + srow16;
    *(uint4*)(&Qs[row * 136 + soff]) =
        *(const uint4*)(Q + ((size_t)(nb * 64 + row) * NH + h) * DH + soff);
  }

  auto stageK = [&](int basePos, int posStride) {
#pragma unroll
    for (int p = 0; p < 4; p++) {
      int row = p * 16 + srow16;
      int pos = basePos + row * posStride;
      uint4 val = make_uint4(0u, 0u, 0u, 0u);
      if (pos >= 0)
        val = *(const uint4*)(Kk + ((size_t)pos * NKV + kvh) * DH + soff);
      *(uint4*)(&kvb[row * 136 + soff]) = val;
    }
  };

  auto stageVt = [&](int basePos, int posStride) {
#pragma unroll
    for (int p = 0; p < 4; p++) {
      int key = p * 16 + srow16;
      int pos = basePos + key * posStride;
      uint4 tv = make_uint4(0u, 0u, 0u, 0u);
      if (pos >= 0)
        tv = *(const uint4*)(V + ((size_t)pos * NKV + kvh) * DH + soff);
      const bf16* tmp = (const bf16*)&tv;
#pragma unroll
      for (int jj = 0; jj < 8; jj++)
        kvb[(soff + jj) * 72 + key] = tmp[jj];
    }
  };

  f32x4 sc[8] = {};
  f32x4 slm[4] = {};

  auto scoreStep = [&](f32x4* dst) {
#pragma unroll
    for (int kk = 0; kk < 128; kk += 32) {
      bf16x8 a = *(const bf16x8*)(&Qs[(wid * 16 + l16) * 136 + kk + quad * 8]);
#pragma unroll
      for (int nt = 0; nt < 4; nt++) {
        bf16x8 b =
            *(const bf16x8*)(&kvb[(nt * 16 + l16) * 136 + kk + quad * 8]);
        dst[nt] = __builtin_amdgcn_mfma_f32_16x16x32_bf16(a, b, dst[nt], 0, 0, 0);
      }
    }
  };

  stageK(nb * 64 - 64, 1);
  __syncthreads();
  scoreStep(&sc[0]);
  __syncthreads();
  stageK(nb * 64, 1);
  __syncthreads();
  scoreStep(&sc[4]);
  __syncthreads();
  stageK(0, 64);
  __syncthreads();
  scoreStep(&slm[0]);
  __syncthreads();

  float invL[4], invG[4];
#pragma unroll
  for (int r = 0; r < 4; r++) {
    const int i = wid * 16 + quad * 4 + r;
    float mx = -1e30f;
#pragma unroll
    for (int nt = 0; nt < 8; nt++) {
      int j = nt * 16 + l16;
      float s = sc[nt][r] * SCALE;
      if (j < i || j > i + 64) s = -1e30f;
      sc[nt][r] = s;
      mx = fmaxf(mx, s);
    }
#pragma unroll
    for (int m = 1; m <= 8; m <<= 1) mx = fmaxf(mx, __shfl_xor(mx, m, 64));
    float sum = 0.f;
#pragma unroll
    for (int nt = 0; nt < 8; nt++) {
      float e = __expf(sc[nt][r] - mx);
      sc[nt][r] = e;
      sum += e;
    }
#pragma unroll
    for (int m = 1; m <= 8; m <<= 1) sum += __shfl_xor(sum, m, 64);
    invL[r] = 0.7f / sum;

    float mg = -1e30f;
#pragma unroll
    for (int nt = 0; nt < 4; nt++) {
      int l = nt * 16 + l16;
      float s = slm[nt][r] * SCALE;
      if (l > nb) s = -1e30f;
      slm[nt][r] = s;
      mg = fmaxf(mg, s);
    }
#pragma unroll
    for (int m = 1; m <= 8; m <<= 1) mg = fmaxf(mg, __shfl_xor(mg, m, 64));
    float sg = 0.f;
#pragma unroll
    for (int nt = 0; nt < 4; nt++) {
      float e = __expf(slm[nt][r] - mg);
      slm[nt][r] = e;
      sg += e;
    }
#pragma unroll
    for (int m = 1; m <= 8; m <<= 1) sg += __shfl_xor(sg, m, 64);
    invG[r] = 0.3f / sg;
  }

#pragma unroll
  for (int nt = 0; nt < 8; nt++)
#pragma unroll
    for (int r = 0; r < 4; r++)
      Qs[(wid * 16 + quad * 4 + r) * 136 + nt * 16 + l16] =
          __float2bfloat16(sc[nt][r]);
#pragma unroll
  for (int nt = 0; nt < 4; nt++)
#pragma unroll
    for (int r = 0; r < 4; r++)
      PLs[(wid * 16 + quad * 4 + r) * 72 + nt * 16 + l16] =
          __float2bfloat16(slm[nt][r]);
  stageVt(nb * 64 - 64, 1);
  __syncthreads();

  f32x4 accO[8] = {};
  f32x4 accG[8] = {};
  auto pvStep = [&](f32x4* dst, const bf16* Pbase, int pstride, int colbase) {
#pragma unroll
    for (int kk = 0; kk < 64; kk += 32) {
      bf16x8 a = *(const bf16x8*)(&Pbase[(wid * 16 + l16) * pstride + colbase +
                                         kk + quad * 8]);
#pragma unroll
      for (int nt = 0; nt < 8; nt++) {
        bf16x8 b = *(const bf16x8*)(&kvb[(nt * 16 + l16) * 72 + kk + quad * 8]);
        dst[nt] = __builtin_amdgcn_mfma_f32_16x16x32_bf16(a, b, dst[nt], 0, 0, 0);
      }
    }
  };
  pvStep(accO, Qs, 136, 0);
  __syncthreads();
  stageVt(nb * 64, 1);
  __syncthreads();
  pvStep(accO, Qs, 136, 64);
  __syncthreads();
  stageVt(0, 64);
  __syncthreads();
  pvStep(accG, PLs, 72, 0);

#pragma unroll
  for (int nt = 0; nt < 8; nt++)
#pragma unroll
    for (int r = 0; r < 4; r++) {
      int q = nb * 64 + wid * 16 + quad * 4 + r;
      int d = nt * 16 + l16;
      float v = accO[nt][r] * invL[r] + accG[nt][r] * invG[r];
      O[((size_t)q * NH + h) * DH + d] = __float2bfloat16(v);
    }
}

// ---------------- launch ----------------
extern "C" void kernel_launch(void* const* d_in, const int* in_sizes, int n_in,
                              void* d_out, int out_size, void* d_ws,
                              size_t ws_size, hipStream_t stream) {
  const void* X  = d_in[0];
  const void* wq = d_in[1];
  const void* wk = d_in[2];
  const void* wv = d_in[3];
  const void* wo = d_in[4];

  char* ws = (char*)d_ws;
  int* flag = (int*)ws;
  bf16* Xb   = (bf16*)(ws + 256);               // 32 MB ; aliased as At
  bf16* Wcat = Xb + (size_t)S_LEN * HIDN;       // 48 MB [6144][4096]
  bf16* Qb   = Wcat + (size_t)6144 * HIDN;      // 32 MB
  bf16* Kb   = Qb + (size_t)S_LEN * HIDN;       // 8 MB
  bf16* Vb   = Kb + (size_t)S_LEN * 1024;       // 8 MB
  bf16* At   = Xb;                              // alias (X dead after QKV)
  bf16* WoT  = Wcat;                            // alias (Wcat dead after QKV)

  k_detect<<<1, 256, 0, stream>>>((const unsigned short*)wq, flag);

  k_cvt<<<(S_LEN * HIDN / 8 + 255) / 256, 256, 0, stream>>>(
      X, Xb, flag, S_LEN * HIDN / 8);
  k_tcvt<<<dim3(HIDN / 64, HIDN / 64), 256, 0, stream>>>(
      wq, Wcat, flag, HIDN, HIDN);
  k_tcvt<<<dim3(HIDN / 64, 1024 / 64), 256, 0, stream>>>(
      wk, Wcat + (size_t)4096 * HIDN, flag, HIDN, 1024);
  k_tcvt<<<dim3(HIDN / 64, 1024 / 64), 256, 0, stream>>>(
      wv, Wcat + (size_t)5120 * HIDN, flag, HIDN, 1024);

  // fused QKV GEMM: [4096][4096] x [6144][4096]^T -> Qb|Kb|Vb
  // 256x128 tiles: 16 x 48 = 768 blocks = 3.0 balanced rounds
  k_gemm<128><<<dim3(S_LEN / 256, 6144 / 128), 512, 0, stream>>>(
      Xb, Wcat, Qb, Kb, Vb, flag, S_LEN, 6144, HIDN, 0);

  int totalQ = S_LEN * NH * 64, total = totalQ + S_LEN * NKV * 64;
  k_rope<<<(total + 255) / 256, 256, 0, stream>>>(Qb, Kb, totalQ, total);

  k_attn<<<dim3(NBLK, NH), 256, 0, stream>>>(Qb, Kb, Vb, At);

  k_tcvt<<<dim3(HIDN / 64, HIDN / 64), 256, 0, stream>>>(
      wo, WoT, flag, HIDN, HIDN);

  // WO GEMM: 256x256 tiles: 16 x 16 = 256 blocks = 1.0 round
  k_gemm<256><<<dim3(S_LEN / 256, HIDN / 256), 512, 0, stream>>>(
      At, WoT, d_out, nullptr, nullptr, flag, S_LEN, HIDN, HIDN, 1);
}